// Round 5
// baseline (214.917 us; speedup 1.0000x reference)
//
#include <hip/hip_runtime.h>

typedef unsigned short u16;
typedef unsigned int u32;
typedef __bf16 bf16x8 __attribute__((ext_vector_type(8)));
typedef float f32x4 __attribute__((ext_vector_type(4)));

#define L_SEQ 2048
#define NH 16
#define DH 64
#define D_MODEL 1024
// shift in exp2 domain: 10*log2(e); q pre-scaled by 0.125*log2(e)
#define ATT_SHIFT2 14.426950408889634f

__device__ __forceinline__ u16 f2bf(float f) {
  union { float f; u32 u; } v; v.f = f;
  u32 u = v.u;
  return (u16)((u + 0x7fffu + ((u >> 16) & 1u)) >> 16);  // RNE
}
__device__ __forceinline__ float bf2f(u16 b) {
  union { u32 u; float f; } v; v.u = ((u32)b) << 16;
  return v.f;
}
// pack two floats -> two bf16 (round-half-up), lo_val in low 16 bits
__device__ __forceinline__ u32 pk2(float lo_val, float hi_val) {
  union { float f; u32 u; } a, b;
  a.f = hi_val; b.f = lo_val;
  return __builtin_amdgcn_perm(a.u + 0x8000u, b.u + 0x8000u, 0x07060302u);
}
// truncating pack (1 inst) — used for P where values are in [0,1]
__device__ __forceinline__ u32 pk2t(float lo_val, float hi_val) {
  union { float f; u32 u; } a, b;
  a.f = hi_val; b.f = lo_val;
  return __builtin_amdgcn_perm(a.u, b.u, 0x07060302u);
}
__device__ __forceinline__ bf16x8 ld8(const u16* p) {
  union { uint4 u; bf16x8 b; } v;
  v.u = *(const uint4*)p;
  return v.b;
}
__device__ __forceinline__ f32x4 fzero4() { f32x4 z = {0.f, 0.f, 0.f, 0.f}; return z; }

__device__ __forceinline__ float fexp2(float x) {
#if __has_builtin(__builtin_amdgcn_exp2f)
  return __builtin_amdgcn_exp2f(x);
#else
  return __expf(x * 0.6931471805599453f);
#endif
}

// async global->LDS: lane i of the wave writes ldsbase + i*16
__device__ __forceinline__ void gll16(const u16* g, u16* l) {
  __builtin_amdgcn_global_load_lds((const __attribute__((address_space(1))) u32*)g,
                                   (__attribute__((address_space(3))) u32*)l, 16, 0, 0);
}

// ---------------- K1: fused fp32 -> bf16 cast of x, w_qkv, w_proj ----------------
__global__ __launch_bounds__(256) void cvt_all(const float* __restrict__ x,
                                               const float* __restrict__ wqkv,
                                               const float* __restrict__ wproj,
                                               u16* __restrict__ xb,
                                               u16* __restrict__ wqkvb,
                                               u16* __restrict__ wprojb) {
  int i = blockIdx.x * 256 + threadIdx.x;  // 0 .. 2097151 float4s
  const float* s;
  u16* d;
  int off;
  if (i < 1048576)      { s = x;     d = xb;     off = i; }
  else if (i < 1835008) { s = wqkv;  d = wqkvb;  off = i - 1048576; }
  else                  { s = wproj; d = wprojb; off = i - 1835008; }
  float4 v = ((const float4*)s)[off];
  ((ushort4*)d)[off] = make_ushort4(f2bf(v.x), f2bf(v.y), f2bf(v.z), f2bf(v.w));
}

// ---------------- K2: QKV GEMM with layout-epilogue ----------------
// C[M=4096, N=3072] = x * w_qkv^T. 128x128 tile, BK=64, m97 staging.
// q,k tiles (n0<2048) written directly to (B,H,L,Dh); v tiles LDS-transposed to (B,H,Dh,L).
__global__ __launch_bounds__(256) void gemm_qkv(const u16* __restrict__ A,
                                                const u16* __restrict__ B,
                                                u16* __restrict__ qb,
                                                u16* __restrict__ kb,
                                                u16* __restrict__ vtb) {
  __shared__ u16 smem[16384];  // As = smem[0:8192), Bs = smem[8192:16384); reused for v-transpose
  u16* As = smem;
  u16* Bs = smem + 8192;
  const int t = threadIdx.x;
  const int lane = t & 63, wv = t >> 6;
  const int col = lane & 15, quad = lane >> 4;
  const int wr = wv >> 1, wc = wv & 1;
  const int m0 = blockIdx.y * 128, n0 = blockIdx.x * 128;

  f32x4 acc[4][4];
#pragma unroll
  for (int i = 0; i < 4; ++i)
#pragma unroll
    for (int j = 0; j < 4; ++j) acc[i][j] = fzero4();

  for (int kt = 0; kt < 1024; kt += 64) {
    __syncthreads();
#pragma unroll
    for (int it = 0; it < 4; ++it) {
      int id0 = it * 256 + wv * 64;  // wave-uniform LDS base (16B units)
      int id = id0 + lane;
      int row = id >> 3, cs = id & 7;
      int csrc = cs ^ (row & 7);     // XOR swizzle
      gll16(A + (size_t)(m0 + row) * 1024 + kt + csrc * 8, As + (size_t)id0 * 8);
      gll16(B + (size_t)(n0 + row) * 1024 + kt + csrc * 8, Bs + (size_t)id0 * 8);
    }
    __syncthreads();
#pragma unroll
    for (int c = 0; c < 2; ++c) {
      bf16x8 af[4], bfv[4];
#pragma unroll
      for (int f = 0; f < 4; ++f) {
        int r = wr * 64 + f * 16 + col;
        af[f] = ld8(&As[(r * 8 + ((c * 4 + quad) ^ (r & 7))) * 8]);
        int rb = wc * 64 + f * 16 + col;
        bfv[f] = ld8(&Bs[(rb * 8 + ((c * 4 + quad) ^ (rb & 7))) * 8]);
      }
#pragma unroll
      for (int i = 0; i < 4; ++i)
#pragma unroll
        for (int j = 0; j < 4; ++j)
          acc[i][j] = __builtin_amdgcn_mfma_f32_16x16x32_bf16(af[i], bfv[j], acc[i][j], 0, 0, 0);
    }
  }

  const int region = n0 >> 10;  // 0=q, 1=k, 2=v (block-uniform)
  if (region < 2) {
    u16* dst = region ? kb : qb;
#pragma unroll
    for (int i = 0; i < 4; ++i) {
      int gr = m0 + wr * 64 + i * 16 + quad * 4;
      int b = gr >> 11, l = gr & 2047;
#pragma unroll
      for (int j = 0; j < 4; ++j) {
        int gc = (n0 & 1023) + wc * 64 + j * 16 + col;
        int h = gc >> 6, dh = gc & 63;
        size_t base = ((size_t)(b * NH + h) * L_SEQ + l) * DH + dh;
#pragma unroll
        for (int r = 0; r < 4; ++r)
          dst[base + (size_t)r * DH] = f2bf(acc[i][j][r]);
      }
    }
  } else {
    // v: transpose the 128x128 C tile through LDS, write dh-major rows
    __syncthreads();  // all waves done reading As/Bs
#pragma unroll
    for (int i = 0; i < 4; ++i) {
      int m_l = wr * 64 + i * 16 + quad * 4;
#pragma unroll
      for (int j = 0; j < 4; ++j) {
        int n_l = wc * 64 + j * 16 + col;
        int ta = n_l * 128 + (m_l ^ ((n_l & 15) << 3));
        *(uint2*)(smem + ta) = make_uint2(pk2(acc[i][j][0], acc[i][j][1]),
                                          pk2(acc[i][j][2], acc[i][j][3]));
      }
    }
    __syncthreads();
    const int b = m0 >> 11, lbase = m0 & 2047;
    const int n_l = t >> 1, mh = (t & 1) * 64;
    const int gc = (n0 - 2048) + n_l;
    const int h = gc >> 6, dh = gc & 63;
    u16* vrow = vtb + ((size_t)(b * NH + h) * DH + dh) * L_SEQ + lbase + mh;
#pragma unroll
    for (int c2 = 0; c2 < 8; ++c2) {
      int m = mh + c2 * 8;
      uint4 v = *(const uint4*)(smem + n_l * 128 + (m ^ ((n_l & 15) << 3)));
      *(uint4*)(vrow + c2 * 8) = v;
    }
  }
}

// ---------------- K3: RMSNorm + RoPE in-place on qb/kb (B,H,L,Dh) ----------------
// Folds softmax scale 0.125 AND log2(e) into q. One wave per (b,l), all 16 heads.
__global__ __launch_bounds__(256) void qk_norm_rope(u16* __restrict__ qb,
                                                    u16* __restrict__ kb,
                                                    const float* __restrict__ rope,
                                                    const float* __restrict__ qw,
                                                    const float* __restrict__ kw) {
  const int t = threadIdx.x;
  const int lane = t & 63, wv = t >> 6;
  const int gid = blockIdx.x * 4 + wv;  // b*L + l
  const int l = gid & (L_SEQ - 1);
  const int b = gid >> 11;
  const int lg = lane & 7;
  const float QSCALE = 0.125f * 1.4426950408889634f;

  float wqv[8], wkv[8], rp[8];
  {
    float4 a = *(const float4*)(qw + lg * 8);
    float4 c = *(const float4*)(qw + lg * 8 + 4);
    wqv[0]=a.x; wqv[1]=a.y; wqv[2]=a.z; wqv[3]=a.w; wqv[4]=c.x; wqv[5]=c.y; wqv[6]=c.z; wqv[7]=c.w;
    a = *(const float4*)(kw + lg * 8);
    c = *(const float4*)(kw + lg * 8 + 4);
    wkv[0]=a.x; wkv[1]=a.y; wkv[2]=a.z; wkv[3]=a.w; wkv[4]=c.x; wkv[5]=c.y; wkv[6]=c.z; wkv[7]=c.w;
    a = *(const float4*)(rope + (size_t)l * 64 + lg * 8);
    c = *(const float4*)(rope + (size_t)l * 64 + lg * 8 + 4);
    rp[0]=a.x; rp[1]=a.y; rp[2]=a.z; rp[3]=a.w; rp[4]=c.x; rp[5]=c.y; rp[6]=c.z; rp[7]=c.w;
  }

#pragma unroll
  for (int i = 0; i < 2; ++i) {
    const int head = i * 8 + (lane >> 3);
    size_t addr = ((size_t)(b * NH + head) * L_SEQ + l) * DH + lg * 8;
    bf16x8 q8 = ld8(qb + addr);
    bf16x8 k8 = ld8(kb + addr);
    float q[8], k[8];
#pragma unroll
    for (int j = 0; j < 8; ++j) { q[j] = (float)q8[j]; k[j] = (float)k8[j]; }
    float sq = 0.f, sk = 0.f;
#pragma unroll
    for (int j = 0; j < 8; ++j) { sq += q[j] * q[j]; sk += k[j] * k[j]; }
    sq += __shfl_xor(sq, 1); sq += __shfl_xor(sq, 2); sq += __shfl_xor(sq, 4);
    sk += __shfl_xor(sk, 1); sk += __shfl_xor(sk, 2); sk += __shfl_xor(sk, 4);
    float qi = rsqrtf(sq * (1.f / 64.f) + 1e-6f);
    float ki = rsqrtf(sk * (1.f / 64.f) + 1e-6f);

    float rq[8], rk[8];
#pragma unroll
    for (int j = 0; j < 4; ++j) {
      float cs = rp[2 * j], sn = rp[2 * j + 1];
      float qe = q[2 * j] * qi * wqv[2 * j], qo = q[2 * j + 1] * qi * wqv[2 * j + 1];
      float ke = k[2 * j] * ki * wkv[2 * j], ko = k[2 * j + 1] * ki * wkv[2 * j + 1];
      rq[2 * j]     = (qe * cs - qo * sn) * QSCALE;
      rq[2 * j + 1] = (qe * sn + qo * cs) * QSCALE;
      rk[2 * j]     = ke * cs - ko * sn;
      rk[2 * j + 1] = ke * sn + ko * cs;
    }
    *(uint4*)(qb + addr) = make_uint4(pk2(rq[0], rq[1]), pk2(rq[2], rq[3]),
                                      pk2(rq[4], rq[5]), pk2(rq[6], rq[7]));
    *(uint4*)(kb + addr) = make_uint4(pk2(rk[0], rk[1]), pk2(rk[2], rk[3]),
                                      pk2(rk[4], rk[5]), pk2(rk[6], rk[7]));
  }
}

// ---------------- K4: flash attention, S^T form, fixed shift, split-K x2 ----------------
// Single-buffer K/V (16 KB) + 4 KB/wave P for both q-frags -> 32 KB LDS, 5 blocks/CU.
// V fragments shared across both q-frags in the PV loop.
__global__ __launch_bounds__(256) void attn_flash(const u16* __restrict__ qb,
                                                  const u16* __restrict__ kb,
                                                  const u16* __restrict__ vtb,
                                                  u16* __restrict__ po,
                                                  float* __restrict__ pl) {
  __shared__ u16 ldsK[4096];   // [key][dh], 16B-chunk XOR swizzled
  __shared__ u16 ldsV[4096];   // [dh][key], swizzled
  __shared__ u16 ldsP[8192];   // per-wave P: 32 q-rows x 64 keys, slot-swizzled
  const int t = threadIdx.x;
  const int lane = t & 63, wv = t >> 6;
  const int col = lane & 15, quad = lane >> 4;
  const int bh = blockIdx.x;
  const int half = blockIdx.z;
  const int q0 = blockIdx.y * 128 + wv * 32;

  const u16* kbase = kb + ((size_t)bh * L_SEQ + half * 1024) * DH;
  const u16* vbase = vtb + (size_t)bh * DH * L_SEQ + half * 1024;

  bf16x8 qfrag[2][2];
#pragma unroll
  for (int qf = 0; qf < 2; ++qf)
#pragma unroll
    for (int c = 0; c < 2; ++c)
      qfrag[qf][c] = ld8(qb + ((size_t)bh * L_SEQ + q0 + qf * 16 + col) * DH + c * 32 + quad * 8);

  f32x4 o[2][4];
#pragma unroll
  for (int qf = 0; qf < 2; ++qf)
#pragma unroll
    for (int nf = 0; nf < 4; ++nf) o[qf][nf] = fzero4();
  float lrow[2] = {0.f, 0.f};

  u16* pb = &ldsP[wv * 2048];

  for (int tt = 0; tt < 16; ++tt) {
    __syncthreads();  // all waves done with previous tile's K/V/P
    {
      const int kt = tt * 64;
#pragma unroll
      for (int it = 0; it < 2; ++it) {
        int id0 = it * 256 + wv * 64;
        int id = id0 + lane;
        int row = id >> 3, cs = id & 7, csrc = cs ^ (row & 7);
        gll16(kbase + (size_t)(kt + row) * DH + csrc * 8, ldsK + (size_t)id0 * 8);
        gll16(vbase + (size_t)row * L_SEQ + kt + csrc * 8, ldsV + (size_t)id0 * 8);
      }
    }
    __syncthreads();  // staging visible (compiler drains vmcnt before barrier)

    // S^T = K Q^T : rows = keys (mf*16 + quad*4 + r), cols = q (col)
    f32x4 s[2][4];
#pragma unroll
    for (int qf = 0; qf < 2; ++qf)
#pragma unroll
      for (int mf = 0; mf < 4; ++mf) s[qf][mf] = fzero4();
#pragma unroll
    for (int c = 0; c < 2; ++c) {
#pragma unroll
      for (int mf = 0; mf < 4; ++mf) {
        int kr = mf * 16 + col;
        bf16x8 kf = ld8(&ldsK[kr * 64 + (((c * 4 + quad) ^ (kr & 7)) * 8)]);
#pragma unroll
        for (int qf = 0; qf < 2; ++qf)
          s[qf][mf] = __builtin_amdgcn_mfma_f32_16x16x32_bf16(kf, qfrag[qf][c], s[qf][mf], 0, 0, 0);
      }
    }

    // exp2 softmax (shift folded); write P for BOTH qf, then shared-vf PV
#pragma unroll
    for (int qf = 0; qf < 2; ++qf) {
      float ts = 0.f;
#pragma unroll
      for (int mf = 0; mf < 4; ++mf)
#pragma unroll
        for (int r = 0; r < 4; ++r) {
          float e = fexp2(s[qf][mf][r] - ATT_SHIFT2);
          s[qf][mf][r] = e;
          ts += e;
        }
      lrow[qf] += ts;  // cross-quad reduce deferred to epilogue
      const int q = qf * 16 + col;
#pragma unroll
      for (int mf = 0; mf < 4; ++mf) {
        int slot = q * 8 + ((2 * mf + (quad >> 1)) ^ (q & 7));
        *(uint2*)(pb + slot * 8 + (quad & 1) * 4) =
            make_uint2(pk2t(s[qf][mf][0], s[qf][mf][1]), pk2t(s[qf][mf][2], s[qf][mf][3]));
      }
    }

#pragma unroll
    for (int c = 0; c < 2; ++c) {
      bf16x8 pa[2];
#pragma unroll
      for (int qf = 0; qf < 2; ++qf) {
        const int q = qf * 16 + col;
        pa[qf] = ld8(pb + (q * 8 + ((c * 4 + quad) ^ (q & 7))) * 8);
      }
#pragma unroll
      for (int nf = 0; nf < 4; ++nf) {
        int vr = nf * 16 + col;
        bf16x8 vf = ld8(&ldsV[vr * 64 + (((c * 4 + quad) ^ (vr & 7)) * 8)]);
#pragma unroll
        for (int qf = 0; qf < 2; ++qf)
          o[qf][nf] = __builtin_amdgcn_mfma_f32_16x16x32_bf16(pa[qf], vf, o[qf][nf], 0, 0, 0);
      }
    }
  }

  // epilogue: finish l reduction, write unnormalized partials
  u16* pob = po + (size_t)(half * 32 + bh) * L_SEQ * DH;
#pragma unroll
  for (int qf = 0; qf < 2; ++qf) {
    lrow[qf] += __shfl_xor(lrow[qf], 16);
    lrow[qf] += __shfl_xor(lrow[qf], 32);
    if (quad == 0)
      pl[(size_t)(half * 32 + bh) * L_SEQ + q0 + qf * 16 + col] = lrow[qf];
#pragma unroll
    for (int nf = 0; nf < 4; ++nf)
#pragma unroll
      for (int r = 0; r < 4; ++r)
        pob[(size_t)(q0 + qf * 16 + quad * 4 + r) * DH + nf * 16 + col] = f2bf(o[qf][nf][r]);
  }
}

// ---------------- K5: proj GEMM with fused split-K combine ----------------
// out[4096,1024] = combined(po)/l * w_proj^T. BM=64, BN=128, BK=64.
__global__ __launch_bounds__(256) void gemm2_cmb(const u16* __restrict__ po,
                                                 const float* __restrict__ pl,
                                                 const u16* __restrict__ B,
                                                 float* __restrict__ out) {
  __shared__ u16 As[64 * 64];
  __shared__ u16 Bs[128 * 64];
  const int t = threadIdx.x;
  const int lane = t & 63, wv = t >> 6;
  const int col = lane & 15, quad = lane >> 4;
  const int wr = wv >> 1, wc = wv & 1;
  const int m0 = blockIdx.y * 64, n0 = blockIdx.x * 128;
  const int srow = t >> 2, kc0 = (t & 3) * 2;
  const int m = m0 + srow, bb = m >> 11, ll = m & 2047;

  f32x4 acc[2][4];
#pragma unroll
  for (int i = 0; i < 2; ++i)
#pragma unroll
    for (int j = 0; j < 4; ++j) acc[i][j] = fzero4();

  for (int kt = 0; kt < 1024; kt += 64) {
    __syncthreads();
    {
      int h = kt >> 6;
      size_t lidx = (size_t)(bb * 16 + h) * L_SEQ + ll;
      float inv = 1.0f / (pl[lidx] + pl[65536 + lidx]);
      size_t rowoff = lidx * 64;
#pragma unroll
      for (int i = 0; i < 2; ++i) {
        int kc = kc0 + i;
        uint4 a0 = *(const uint4*)(po + rowoff + kc * 8);
        uint4 a1 = *(const uint4*)(po + 4194304 + rowoff + kc * 8);
        union { uint4 u; u16 s[8]; } ua, ub;
        ua.u = a0; ub.u = a1;
        float r[8];
#pragma unroll
        for (int j = 0; j < 8; ++j) r[j] = (bf2f(ua.s[j]) + bf2f(ub.s[j])) * inv;
        uint4 pk = make_uint4(pk2(r[0], r[1]), pk2(r[2], r[3]), pk2(r[4], r[5]), pk2(r[6], r[7]));
        int slot = srow * 8 + (kc ^ (srow & 7));
        *(uint4*)(As + slot * 8) = pk;
      }
    }
#pragma unroll
    for (int it = 0; it < 4; ++it) {
      int id0 = it * 256 + wv * 64;
      int id = id0 + lane;
      int row = id >> 3, cs = id & 7, csrc = cs ^ (row & 7);
      gll16(B + (size_t)(n0 + row) * 1024 + kt + csrc * 8, Bs + (size_t)id0 * 8);
    }
    __syncthreads();
#pragma unroll
    for (int c = 0; c < 2; ++c) {
      bf16x8 af[2], bfv[4];
#pragma unroll
      for (int f = 0; f < 2; ++f) {
        int r = wr * 32 + f * 16 + col;
        af[f] = ld8(&As[(r * 8 + ((c * 4 + quad) ^ (r & 7))) * 8]);
      }
#pragma unroll
      for (int f = 0; f < 4; ++f) {
        int rb = wc * 64 + f * 16 + col;
        bfv[f] = ld8(&Bs[(rb * 8 + ((c * 4 + quad) ^ (rb & 7))) * 8]);
      }
#pragma unroll
      for (int i = 0; i < 2; ++i)
#pragma unroll
        for (int j = 0; j < 4; ++j)
          acc[i][j] = __builtin_amdgcn_mfma_f32_16x16x32_bf16(af[i], bfv[j], acc[i][j], 0, 0, 0);
    }
  }
#pragma unroll
  for (int i = 0; i < 2; ++i) {
    int gr = m0 + wr * 32 + i * 16 + quad * 4;
#pragma unroll
    for (int j = 0; j < 4; ++j) {
      int gc = n0 + wc * 64 + j * 16 + col;
#pragma unroll
      for (int r = 0; r < 4; ++r)
        out[(size_t)(gr + r) * D_MODEL + gc] = acc[i][j][r];
    }
  }
}

// ---------------- launcher ----------------
extern "C" void kernel_launch(void* const* d_in, const int* in_sizes, int n_in,
                              void* d_out, int out_size, void* d_ws, size_t ws_size,
                              hipStream_t stream) {
  const float* x     = (const float*)d_in[0];
  const float* rope  = (const float*)d_in[1];
  const float* wqkv  = (const float*)d_in[2];
  const float* wproj = (const float*)d_in[3];
  const float* qnw   = (const float*)d_in[4];
  const float* knw   = (const float*)d_in[5];
  float* out = (float*)d_out;
  char* ws = (char*)d_ws;

  u16* xb     = (u16*)(ws + 0);          //  8 MB  bf16 x (4096x1024)
  u16* wqkvb  = (u16*)(ws + 8388608);    //  6 MB  bf16 w_qkv (3072x1024)
  u16* wprojb = (u16*)(ws + 14680064);   //  2 MB  bf16 w_proj (1024x1024)
  u16* qb     = (u16*)(ws + 16777216);   //  8 MB  bf16 q (B,H,L,Dh)
  u16* kb     = (u16*)(ws + 25165824);   //  8 MB  bf16 k (B,H,L,Dh)
  u16* vtb    = (u16*)(ws + 33554432);   //  8 MB  bf16 v^T (B,H,Dh,L)
  u16* po     = (u16*)(ws + 41943040);   // 16 MB  bf16 o-partials [half][bh][q][dh]
  float* pl   = (float*)(ws + 58720256); // 512 KB f32 l-partials [half][bh][q]

  cvt_all<<<8192, 256, 0, stream>>>(x, wqkv, wproj, xb, wqkvb, wprojb);

  gemm_qkv<<<dim3(24, 32), 256, 0, stream>>>(xb, wqkvb, qb, kb, vtb);

  qk_norm_rope<<<1024, 256, 0, stream>>>(qb, kb, rope, qnw, knw);

  attn_flash<<<dim3(32, 16, 2), 256, 0, stream>>>(qb, kb, vtb, po, pl);

  gemm2_cmb<<<dim3(8, 64), 256, 0, stream>>>(po, pl, wprojb, out);
}

// Round 6
// 208.025 us; speedup vs baseline: 1.0331x; 1.0331x over previous
//
#include <hip/hip_runtime.h>

typedef unsigned short u16;
typedef unsigned int u32;
typedef __bf16 bf16x8 __attribute__((ext_vector_type(8)));
typedef float f32x4 __attribute__((ext_vector_type(4)));

#define L_SEQ 2048
#define NH 16
#define DH 64
#define D_MODEL 1024
// shift in exp2 domain: 10*log2(e); q pre-scaled by 0.125*log2(e)
#define ATT_SHIFT2 14.426950408889634f
#define QSCALE_LOG2E 0.18033688011112042f  // 0.125 * log2(e)

__device__ __forceinline__ u16 f2bf(float f) {
  union { float f; u32 u; } v; v.f = f;
  u32 u = v.u;
  return (u16)((u + 0x7fffu + ((u >> 16) & 1u)) >> 16);  // RNE
}
__device__ __forceinline__ float bf2f(u16 b) {
  union { u32 u; float f; } v; v.u = ((u32)b) << 16;
  return v.f;
}
// pack two floats -> two bf16 (round-half-up), lo_val in low 16 bits
__device__ __forceinline__ u32 pk2(float lo_val, float hi_val) {
  union { float f; u32 u; } a, b;
  a.f = hi_val; b.f = lo_val;
  return __builtin_amdgcn_perm(a.u + 0x8000u, b.u + 0x8000u, 0x07060302u);
}
// truncating pack (1 inst) — used for P where values are in [0,1]
__device__ __forceinline__ u32 pk2t(float lo_val, float hi_val) {
  union { float f; u32 u; } a, b;
  a.f = hi_val; b.f = lo_val;
  return __builtin_amdgcn_perm(a.u, b.u, 0x07060302u);
}
__device__ __forceinline__ bf16x8 ld8(const u16* p) {
  union { uint4 u; bf16x8 b; } v;
  v.u = *(const uint4*)p;
  return v.b;
}
__device__ __forceinline__ f32x4 fzero4() { f32x4 z = {0.f, 0.f, 0.f, 0.f}; return z; }

__device__ __forceinline__ float fexp2(float x) {
#if __has_builtin(__builtin_amdgcn_exp2f)
  return __builtin_amdgcn_exp2f(x);
#else
  return __expf(x * 0.6931471805599453f);
#endif
}

// async global->LDS: lane i of the wave writes ldsbase + i*16
__device__ __forceinline__ void gll16(const u16* g, u16* l) {
  __builtin_amdgcn_global_load_lds((const __attribute__((address_space(1))) u32*)g,
                                   (__attribute__((address_space(3))) u32*)l, 16, 0, 0);
}

// ---------------- K1: fused fp32 -> bf16 cast of x, w_qkv, w_proj ----------------
__global__ __launch_bounds__(256) void cvt_all(const float* __restrict__ x,
                                               const float* __restrict__ wqkv,
                                               const float* __restrict__ wproj,
                                               u16* __restrict__ xb,
                                               u16* __restrict__ wqkvb,
                                               u16* __restrict__ wprojb) {
  int i = blockIdx.x * 256 + threadIdx.x;  // 0 .. 2097151 float4s
  const float* s;
  u16* d;
  int off;
  if (i < 1048576)      { s = x;     d = xb;     off = i; }
  else if (i < 1835008) { s = wqkv;  d = wqkvb;  off = i - 1048576; }
  else                  { s = wproj; d = wprojb; off = i - 1835008; }
  float4 v = ((const float4*)s)[off];
  ((ushort4*)d)[off] = make_ushort4(f2bf(v.x), f2bf(v.y), f2bf(v.z), f2bf(v.w));
}

// ---------------- K2: QKV GEMM with fused RMSNorm+RoPE / v-transpose epilogue ----
// C[4096,3072] = x * w_qkv^T. 128x128 tile, BK=64, m97 staging.
// q/k tiles: rmsnorm (f32 acc!) + rope + (q: scale) applied in-epilogue, written
// to (B,H,L,Dh). v tiles: LDS-transposed to (B,H,Dh,L).
__global__ __launch_bounds__(256) void gemm_qkv(const u16* __restrict__ A,
                                                const u16* __restrict__ B,
                                                const float* __restrict__ rope,
                                                const float* __restrict__ qw,
                                                const float* __restrict__ kw,
                                                u16* __restrict__ qb,
                                                u16* __restrict__ kb,
                                                u16* __restrict__ vtb) {
  __shared__ u16 smem[16384];  // As=[0:8192), Bs=[8192:16384); reused for v-transpose
  u16* As = smem;
  u16* Bs = smem + 8192;
  const int t = threadIdx.x;
  const int lane = t & 63, wv = t >> 6;
  const int col = lane & 15, quad = lane >> 4;
  const int wr = wv >> 1, wc = wv & 1;
  const int m0 = blockIdx.y * 128, n0 = blockIdx.x * 128;

  f32x4 acc[4][4];
#pragma unroll
  for (int i = 0; i < 4; ++i)
#pragma unroll
    for (int j = 0; j < 4; ++j) acc[i][j] = fzero4();

  for (int kt = 0; kt < 1024; kt += 64) {
    __syncthreads();
#pragma unroll
    for (int it = 0; it < 4; ++it) {
      int id0 = it * 256 + wv * 64;  // wave-uniform LDS base (16B units)
      int id = id0 + lane;
      int row = id >> 3, cs = id & 7;
      int csrc = cs ^ (row & 7);     // XOR swizzle
      gll16(A + (size_t)(m0 + row) * 1024 + kt + csrc * 8, As + (size_t)id0 * 8);
      gll16(B + (size_t)(n0 + row) * 1024 + kt + csrc * 8, Bs + (size_t)id0 * 8);
    }
    __syncthreads();
#pragma unroll
    for (int c = 0; c < 2; ++c) {
      bf16x8 af[4], bfv[4];
#pragma unroll
      for (int f = 0; f < 4; ++f) {
        int r = wr * 64 + f * 16 + col;
        af[f] = ld8(&As[(r * 8 + ((c * 4 + quad) ^ (r & 7))) * 8]);
        int rb = wc * 64 + f * 16 + col;
        bfv[f] = ld8(&Bs[(rb * 8 + ((c * 4 + quad) ^ (rb & 7))) * 8]);
      }
#pragma unroll
      for (int i = 0; i < 4; ++i)
#pragma unroll
        for (int j = 0; j < 4; ++j)
          acc[i][j] = __builtin_amdgcn_mfma_f32_16x16x32_bf16(af[i], bfv[j], acc[i][j], 0, 0, 0);
    }
  }

  const int region = n0 >> 10;  // 0=q, 1=k, 2=v (block-uniform)
  if (region < 2) {
    // fused RMSNorm + RoPE. One (row,head) is fully owned by one wave:
    // head = (n0&1023)/64 + wc; dh = j*16+col; row picked by (i,quad,r).
    const float* w = region ? kw : qw;
    u16* dst = region ? kb : qb;
    const float scale = region ? 1.0f : QSCALE_LOG2E;
    const int h = ((n0 & 1023) >> 6) + wc;
    float wloc[4];
#pragma unroll
    for (int j = 0; j < 4; ++j) wloc[j] = w[j * 16 + col];
#pragma unroll
    for (int i = 0; i < 4; ++i) {
#pragma unroll
      for (int r = 0; r < 4; ++r) {
        float v0 = acc[i][0][r], v1 = acc[i][1][r], v2 = acc[i][2][r], v3 = acc[i][3][r];
        float ss = v0 * v0 + v1 * v1 + v2 * v2 + v3 * v3;
        ss += __shfl_xor(ss, 1); ss += __shfl_xor(ss, 2);
        ss += __shfl_xor(ss, 4); ss += __shfl_xor(ss, 8);
        float inv = rsqrtf(ss * (1.f / 64.f) + 1e-6f);
        int gr = m0 + wr * 64 + i * 16 + quad * 4 + r;
        int b = gr >> 11, l = gr & 2047;
        const float2* rope2 = (const float2*)rope + (size_t)l * 32;
        size_t obase = ((size_t)(b * NH + h) * L_SEQ + l) * DH;
        float vv[4] = {v0, v1, v2, v3};
#pragma unroll
        for (int j = 0; j < 4; ++j) {
          float val = vv[j] * inv * wloc[j];
          float part = __shfl_xor(val, 1);
          float2 cs = rope2[j * 8 + (col >> 1)];
          float outv = (lane & 1) ? (part * cs.y + val * cs.x)
                                  : (val * cs.x - part * cs.y);
          dst[obase + j * 16 + col] = f2bf(outv * scale);
        }
      }
    }
  } else {
    // v: transpose the 128x128 C tile through LDS, write dh-major rows
    __syncthreads();  // all waves done reading As/Bs
#pragma unroll
    for (int i = 0; i < 4; ++i) {
      int m_l = wr * 64 + i * 16 + quad * 4;
#pragma unroll
      for (int j = 0; j < 4; ++j) {
        int n_l = wc * 64 + j * 16 + col;
        int ta = n_l * 128 + (m_l ^ ((n_l & 15) << 3));
        *(uint2*)(smem + ta) = make_uint2(pk2(acc[i][j][0], acc[i][j][1]),
                                          pk2(acc[i][j][2], acc[i][j][3]));
      }
    }
    __syncthreads();
    const int b = m0 >> 11, lbase = m0 & 2047;
    const int n_l = t >> 1, mh = (t & 1) * 64;
    const int gc = (n0 - 2048) + n_l;
    const int h = gc >> 6, dh = gc & 63;
    u16* vrow = vtb + ((size_t)(b * NH + h) * DH + dh) * L_SEQ + lbase + mh;
#pragma unroll
    for (int c2 = 0; c2 < 8; ++c2) {
      int m = mh + c2 * 8;
      uint4 v = *(const uint4*)(smem + n_l * 128 + (m ^ ((n_l & 15) << 3)));
      *(uint4*)(vrow + c2 * 8) = v;
    }
  }
}

// ---------------- K3: flash attention, S^T form, fixed shift, split-K x2 ----------------
// Wave = 64 q rows (4 frags), block = 256 q rows. K/V single-buffer 16 KB + 32 KB P
// (full 64q x 64k per wave) -> 48 KB LDS, 3 blocks/CU. kf/vf shared across all 4 q-frags.
__global__ __launch_bounds__(256) void attn_flash(const u16* __restrict__ qb,
                                                  const u16* __restrict__ kb,
                                                  const u16* __restrict__ vtb,
                                                  u16* __restrict__ po,
                                                  float* __restrict__ pl) {
  __shared__ u16 ldsK[4096];    // [key][dh], 16B-chunk XOR swizzled
  __shared__ u16 ldsV[4096];    // [dh][key], swizzled
  __shared__ u16 ldsP[16384];   // per-wave P: 64 q-rows x 64 keys, slot-swizzled
  const int t = threadIdx.x;
  const int lane = t & 63, wv = t >> 6;
  const int col = lane & 15, quad = lane >> 4;
  const int bh = blockIdx.x;
  const int half = blockIdx.z;
  const int q0 = blockIdx.y * 256 + wv * 64;

  const u16* kbase = kb + ((size_t)bh * L_SEQ + half * 1024) * DH;
  const u16* vbase = vtb + (size_t)bh * DH * L_SEQ + half * 1024;

  bf16x8 qfrag[4][2];
#pragma unroll
  for (int qf = 0; qf < 4; ++qf)
#pragma unroll
    for (int c = 0; c < 2; ++c)
      qfrag[qf][c] = ld8(qb + ((size_t)bh * L_SEQ + q0 + qf * 16 + col) * DH + c * 32 + quad * 8);

  f32x4 o[4][4];
#pragma unroll
  for (int qf = 0; qf < 4; ++qf)
#pragma unroll
    for (int nf = 0; nf < 4; ++nf) o[qf][nf] = fzero4();
  float lrow[4] = {0.f, 0.f, 0.f, 0.f};

  u16* pb = &ldsP[wv * 4096];
  const int kc_w = (quad >> 1);      // write sub-chunk select
  const int sub = (quad & 1) * 4;    // u16 offset within 16B slot

  for (int tt = 0; tt < 16; ++tt) {
    __syncthreads();  // all waves done with previous tile's K/V
    {
      const int kt = tt * 64;
#pragma unroll
      for (int it = 0; it < 2; ++it) {
        int id0 = it * 256 + wv * 64;
        int id = id0 + lane;
        int row = id >> 3, cs = id & 7, csrc = cs ^ (row & 7);
        gll16(kbase + (size_t)(kt + row) * DH + csrc * 8, ldsK + (size_t)id0 * 8);
        gll16(vbase + (size_t)row * L_SEQ + kt + csrc * 8, ldsV + (size_t)id0 * 8);
      }
    }
    __syncthreads();  // staging visible

    // S^T = K Q^T, one key-frag (mf) at a time: kf shared across all 4 q-frags,
    // s transient (16 VGPRs), exp+P-write immediately per mf.
#pragma unroll
    for (int mf = 0; mf < 4; ++mf) {
      const int kr = mf * 16 + col;
      bf16x8 kf0 = ld8(&ldsK[kr * 64 + (((0 + quad) ^ (kr & 7)) * 8)]);
      bf16x8 kf1 = ld8(&ldsK[kr * 64 + (((4 + quad) ^ (kr & 7)) * 8)]);
      f32x4 s[4];
#pragma unroll
      for (int qf = 0; qf < 4; ++qf) {
        s[qf] = __builtin_amdgcn_mfma_f32_16x16x32_bf16(kf0, qfrag[qf][0], fzero4(), 0, 0, 0);
        s[qf] = __builtin_amdgcn_mfma_f32_16x16x32_bf16(kf1, qfrag[qf][1], s[qf], 0, 0, 0);
      }
      const int kc = mf * 2 + kc_w;  // data key-chunk (8 keys) index
#pragma unroll
      for (int qf = 0; qf < 4; ++qf) {
        float e0 = fexp2(s[qf][0] - ATT_SHIFT2);
        float e1 = fexp2(s[qf][1] - ATT_SHIFT2);
        float e2 = fexp2(s[qf][2] - ATT_SHIFT2);
        float e3 = fexp2(s[qf][3] - ATT_SHIFT2);
        lrow[qf] += (e0 + e1) + (e2 + e3);
        const int q = qf * 16 + col;
        const int slot = q * 8 + (kc ^ (q & 7));
        *(uint2*)(pb + slot * 8 + sub) = make_uint2(pk2t(e0, e1), pk2t(e2, e3));
      }
    }

    // O += P V : vf shared across all 4 q-frags
#pragma unroll
    for (int c = 0; c < 2; ++c) {
      bf16x8 pa[4];
#pragma unroll
      for (int qf = 0; qf < 4; ++qf) {
        const int q = qf * 16 + col;
        pa[qf] = ld8(pb + (q * 8 + ((c * 4 + quad) ^ (q & 7))) * 8);
      }
#pragma unroll
      for (int nf = 0; nf < 4; ++nf) {
        int vr = nf * 16 + col;
        bf16x8 vf = ld8(&ldsV[vr * 64 + (((c * 4 + quad) ^ (vr & 7)) * 8)]);
#pragma unroll
        for (int qf = 0; qf < 4; ++qf)
          o[qf][nf] = __builtin_amdgcn_mfma_f32_16x16x32_bf16(pa[qf], vf, o[qf][nf], 0, 0, 0);
      }
    }
  }

  // epilogue: finish l reduction, write unnormalized partials
  u16* pob = po + (size_t)(half * 32 + bh) * L_SEQ * DH;
#pragma unroll
  for (int qf = 0; qf < 4; ++qf) {
    lrow[qf] += __shfl_xor(lrow[qf], 16);
    lrow[qf] += __shfl_xor(lrow[qf], 32);
    if (quad == 0)
      pl[(size_t)(half * 32 + bh) * L_SEQ + q0 + qf * 16 + col] = lrow[qf];
#pragma unroll
    for (int nf = 0; nf < 4; ++nf)
#pragma unroll
      for (int r = 0; r < 4; ++r)
        pob[(size_t)(q0 + qf * 16 + quad * 4 + r) * DH + nf * 16 + col] = f2bf(o[qf][nf][r]);
  }
}

// ---------------- K4: proj GEMM with fused split-K combine ----------------
// out[4096,1024] = combined(po)/l * w_proj^T. BM=64, BN=128, BK=64.
__global__ __launch_bounds__(256) void gemm2_cmb(const u16* __restrict__ po,
                                                 const float* __restrict__ pl,
                                                 const u16* __restrict__ B,
                                                 float* __restrict__ out) {
  __shared__ u16 As[64 * 64];
  __shared__ u16 Bs[128 * 64];
  const int t = threadIdx.x;
  const int lane = t & 63, wv = t >> 6;
  const int col = lane & 15, quad = lane >> 4;
  const int wr = wv >> 1, wc = wv & 1;
  const int m0 = blockIdx.y * 64, n0 = blockIdx.x * 128;
  const int srow = t >> 2, kc0 = (t & 3) * 2;
  const int m = m0 + srow, bb = m >> 11, ll = m & 2047;

  f32x4 acc[2][4];
#pragma unroll
  for (int i = 0; i < 2; ++i)
#pragma unroll
    for (int j = 0; j < 4; ++j) acc[i][j] = fzero4();

  for (int kt = 0; kt < 1024; kt += 64) {
    __syncthreads();
    {
      int h = kt >> 6;
      size_t lidx = (size_t)(bb * 16 + h) * L_SEQ + ll;
      float inv = 1.0f / (pl[lidx] + pl[65536 + lidx]);
      size_t rowoff = lidx * 64;
#pragma unroll
      for (int i = 0; i < 2; ++i) {
        int kc = kc0 + i;
        uint4 a0 = *(const uint4*)(po + rowoff + kc * 8);
        uint4 a1 = *(const uint4*)(po + 4194304 + rowoff + kc * 8);
        union { uint4 u; u16 s[8]; } ua, ub;
        ua.u = a0; ub.u = a1;
        float r[8];
#pragma unroll
        for (int j = 0; j < 8; ++j) r[j] = (bf2f(ua.s[j]) + bf2f(ub.s[j])) * inv;
        uint4 pk = make_uint4(pk2(r[0], r[1]), pk2(r[2], r[3]), pk2(r[4], r[5]), pk2(r[6], r[7]));
        int slot = srow * 8 + (kc ^ (srow & 7));
        *(uint4*)(As + slot * 8) = pk;
      }
    }
#pragma unroll
    for (int it = 0; it < 4; ++it) {
      int id0 = it * 256 + wv * 64;
      int id = id0 + lane;
      int row = id >> 3, cs = id & 7, csrc = cs ^ (row & 7);
      gll16(B + (size_t)(n0 + row) * 1024 + kt + csrc * 8, Bs + (size_t)id0 * 8);
    }
    __syncthreads();
#pragma unroll
    for (int c = 0; c < 2; ++c) {
      bf16x8 af[2], bfv[4];
#pragma unroll
      for (int f = 0; f < 2; ++f) {
        int r = wr * 32 + f * 16 + col;
        af[f] = ld8(&As[(r * 8 + ((c * 4 + quad) ^ (r & 7))) * 8]);
      }
#pragma unroll
      for (int f = 0; f < 4; ++f) {
        int rb = wc * 64 + f * 16 + col;
        bfv[f] = ld8(&Bs[(rb * 8 + ((c * 4 + quad) ^ (rb & 7))) * 8]);
      }
#pragma unroll
      for (int i = 0; i < 2; ++i)
#pragma unroll
        for (int j = 0; j < 4; ++j)
          acc[i][j] = __builtin_amdgcn_mfma_f32_16x16x32_bf16(af[i], bfv[j], acc[i][j], 0, 0, 0);
    }
  }
#pragma unroll
  for (int i = 0; i < 2; ++i) {
    int gr = m0 + wr * 32 + i * 16 + quad * 4;
#pragma unroll
    for (int j = 0; j < 4; ++j) {
      int gc = n0 + wc * 64 + j * 16 + col;
#pragma unroll
      for (int r = 0; r < 4; ++r)
        out[(size_t)(gr + r) * D_MODEL + gc] = acc[i][j][r];
    }
  }
}

// ---------------- launcher ----------------
extern "C" void kernel_launch(void* const* d_in, const int* in_sizes, int n_in,
                              void* d_out, int out_size, void* d_ws, size_t ws_size,
                              hipStream_t stream) {
  const float* x     = (const float*)d_in[0];
  const float* rope  = (const float*)d_in[1];
  const float* wqkv  = (const float*)d_in[2];
  const float* wproj = (const float*)d_in[3];
  const float* qnw   = (const float*)d_in[4];
  const float* knw   = (const float*)d_in[5];
  float* out = (float*)d_out;
  char* ws = (char*)d_ws;

  u16* xb     = (u16*)(ws + 0);          //  8 MB  bf16 x (4096x1024)
  u16* wqkvb  = (u16*)(ws + 8388608);    //  6 MB  bf16 w_qkv (3072x1024)
  u16* wprojb = (u16*)(ws + 14680064);   //  2 MB  bf16 w_proj (1024x1024)
  u16* qb     = (u16*)(ws + 16777216);   //  8 MB  bf16 q (B,H,L,Dh), normed+roped+scaled
  u16* kb     = (u16*)(ws + 25165824);   //  8 MB  bf16 k (B,H,L,Dh), normed+roped
  u16* vtb    = (u16*)(ws + 33554432);   //  8 MB  bf16 v^T (B,H,Dh,L)
  u16* po     = (u16*)(ws + 41943040);   // 16 MB  bf16 o-partials [half][bh][q][dh]
  float* pl   = (float*)(ws + 58720256); // 512 KB f32 l-partials [half][bh][q]

  cvt_all<<<8192, 256, 0, stream>>>(x, wqkv, wproj, xb, wqkvb, wprojb);

  gemm_qkv<<<dim3(24, 32), 256, 0, stream>>>(xb, wqkvb, rope, qnw, knw, qb, kb, vtb);

  attn_flash<<<dim3(32, 8, 2), 256, 0, stream>>>(qb, kb, vtb, po, pl);

  gemm2_cmb<<<dim3(8, 64), 256, 0, stream>>>(po, pl, wprojb, out);
}